// Round 1
// baseline (126.864 us; speedup 1.0000x reference)
//
#include <hip/hip_runtime.h>

// ContextVector additive-attention (Bahdanau) fused kernel set.
// Shapes (fixed by the problem):
//   encoder_outputs: (8, 512, 256) f32
//   decoder_states:  (8, 256, 512) f32
//   W_enc: (256,256)  W_dec: (512,256)  v: (256,1)
// Outputs: context (8,256,256) then weights (8,256,512), f32, concat in d_out.

constexpr int B  = 8;
constexpr int TE = 512;   // T_enc
constexpr int DE = 256;   // D_enc
constexpr int TD = 256;   // T_dec
constexpr int DD = 512;   // D_dec

constexpr float LOG2E = 1.4426950408889634f;
constexpr float K2    = 2.8853900817779268f;   // 2*log2(e): exp2(K2*z) == exp(2z)

__device__ __forceinline__ float fexp2(float x){ return __builtin_amdgcn_exp2f(x); }
__device__ __forceinline__ float frcp (float x){ return __builtin_amdgcn_rcpf(x); }

// Kernel A: encWT[b][e][t] = sum_k enc[b][t][k] * Wenc[k][e]   (transposed store)
// grid: 16 row-groups x 32 e-groups = 512 blocks, 256 threads.
// Each thread owns one global row (b,t) and 8 e-columns staged in LDS.
__global__ __launch_bounds__(256)
void encw_kernel(const float* __restrict__ enc, const float* __restrict__ Wenc,
                 float* __restrict__ encWT)
{
  __shared__ __align__(16) float Ws[8*256];   // Ws[i][k] = Wenc[k][e0+i]
  const int tid = threadIdx.x;
  const int rg = blockIdx.x >> 5;   // 16 row groups of 256 rows
  const int eg = blockIdx.x & 31;   // 32 e-groups of 8 cols
  const int e0 = eg*8;
  {
    const float* wsrc = Wenc + tid*DE + e0;   // thread tid stages k=tid
    #pragma unroll
    for (int i=0;i<8;i++) Ws[i*256 + tid] = wsrc[i];
  }
  __syncthreads();
  const int row = rg*256 + tid;     // [0,4096): 256 | 512 so rows don't cross b
  const int b = row >> 9;
  const int t = row & (TE-1);
  const float* rp = enc + row*DE;
  float acc[8];
  #pragma unroll
  for (int i=0;i<8;i++) acc[i]=0.f;
  #pragma unroll 4
  for (int k4=0;k4<DE/4;k4++){
    const float4 a = *(const float4*)(rp + 4*k4);
    #pragma unroll
    for (int i=0;i<8;i++){
      const float4 w = *(const float4*)(&Ws[i*256 + 4*k4]);   // LDS broadcast
      acc[i] += a.x*w.x + a.y*w.y + a.z*w.z + a.w*w.w;
    }
  }
  float* op = encWT + (size_t)(b*DE + e0)*TE + t;   // coalesced (t = lane-contig)
  #pragma unroll
  for (int i=0;i<8;i++) op[i*TE] = acc[i];
}

// Main kernel: one block per (b, 4 decoder steps). 512 blocks, 256 threads.
// phase0: dw[s][e] = K2 * (dec[b,s,:] @ Wdec[:,e])
// phase1: acc[s][t] = sum_e v[e] * rcp(1 + exp2(K2*encWT[b][e][t] + dw[s][e]))
//         (tanh(z) = 1 - 2r; the constant sum(v) cancels in softmax)
// phase2: per-wave softmax over t (wave w owns s=w); writes weights output
// phase3: context[s][e] = (sum_t expv[s][t]*enc[b][t][e]) / sum[s]
__global__ __launch_bounds__(256)
void attn_kernel(const float* __restrict__ enc, const float* __restrict__ dec,
                 const float* __restrict__ Wdec, const float* __restrict__ v,
                 const float* __restrict__ encWT,
                 float* __restrict__ outCtx, float* __restrict__ outW)
{
  __shared__ __align__(16) float Ds[4*DD];    // 8 KB: 4 dec rows
  __shared__ __align__(16) float dwT[DE*4];   // 4 KB: [e][s], pre-scaled by K2
  __shared__ float vv[DE];                    // 1 KB
  __shared__ __align__(16) float pl[4*TE];    // 8 KB: alpha -> exp values
  __shared__ float rs[4];
  const int tid = threadIdx.x;
  const int b  = blockIdx.x >> 6;
  const int s0 = (blockIdx.x & 63)*4;

  {
    const float* src = dec + (size_t)(b*TD + s0)*DD;   // 4 contiguous rows
    #pragma unroll
    for (int i=0;i<8;i++) Ds[i*256 + tid] = src[i*256 + tid];
    vv[tid] = v[tid];
  }
  __syncthreads();

  // ---- phase 0: decoder projection (thread = output column e) ----
  {
    float a0=0.f,a1=0.f,a2=0.f,a3=0.f;
    #pragma unroll 2
    for (int d4=0; d4<DD/4; d4++){
      const float4 q0 = *(const float4*)&Ds[0*DD+4*d4];   // LDS broadcast
      const float4 q1 = *(const float4*)&Ds[1*DD+4*d4];
      const float4 q2 = *(const float4*)&Ds[2*DD+4*d4];
      const float4 q3 = *(const float4*)&Ds[3*DD+4*d4];
      const float* wp = Wdec + 4*d4*DE + tid;             // coalesced
      const float w0 = wp[0];
      const float w1 = wp[DE];
      const float w2 = wp[2*DE];
      const float w3 = wp[3*DE];
      a0 += q0.x*w0+q0.y*w1+q0.z*w2+q0.w*w3;
      a1 += q1.x*w0+q1.y*w1+q1.z*w2+q1.w*w3;
      a2 += q2.x*w0+q2.y*w1+q2.z*w2+q2.w*w3;
      a3 += q3.x*w0+q3.y*w1+q3.z*w2+q3.w*w3;
    }
    float4 o; o.x=a0*K2; o.y=a1*K2; o.z=a2*K2; o.w=a3*K2;
    *(float4*)&dwT[tid*4] = o;
  }
  __syncthreads();

  // ---- phase 1: energies (thread owns t=2*tid, 2*tid+1; coalesced encWT) ----
  float acc[8];
  #pragma unroll
  for (int i=0;i<8;i++) acc[i]=0.f;
  const float* ep = encWT + (size_t)(b*DE)*TE + 2*tid;
  #pragma unroll 4
  for (int e=0;e<DE;e++){
    const float2 x = *(const float2*)(ep + e*TE);
    const float kx0 = x.x*K2, kx1 = x.y*K2;
    const float4 dw = *(const float4*)&dwT[e*4];   // LDS broadcast b128
    const float ve = vv[e];                        // LDS broadcast b32
    acc[0] += ve*frcp(1.f+fexp2(kx0+dw.x));
    acc[1] += ve*frcp(1.f+fexp2(kx1+dw.x));
    acc[2] += ve*frcp(1.f+fexp2(kx0+dw.y));
    acc[3] += ve*frcp(1.f+fexp2(kx1+dw.y));
    acc[4] += ve*frcp(1.f+fexp2(kx0+dw.z));
    acc[5] += ve*frcp(1.f+fexp2(kx1+dw.z));
    acc[6] += ve*frcp(1.f+fexp2(kx0+dw.w));
    acc[7] += ve*frcp(1.f+fexp2(kx1+dw.w));
  }
  #pragma unroll
  for (int s=0;s<4;s++){
    float2 st; st.x = -2.f*acc[2*s]; st.y = -2.f*acc[2*s+1];  // alpha = -2*acc (+const)
    *(float2*)&pl[s*TE + 2*tid] = st;
  }
  __syncthreads();

  // ---- phase 2: softmax, wave w handles s=w ----
  {
    const int wv = tid>>6, lane = tid&63;
    float vals[8]; float m = -3.0e38f;
    #pragma unroll
    for (int i=0;i<8;i++){ vals[i] = pl[wv*TE + i*64 + lane]; m = fmaxf(m, vals[i]); }
    #pragma unroll
    for (int off=32; off>=1; off>>=1) m = fmaxf(m, __shfl_xor(m, off));
    float sum = 0.f;
    #pragma unroll
    for (int i=0;i<8;i++){
      float e2 = fexp2((vals[i]-m)*LOG2E);
      vals[i]=e2; sum+=e2; pl[wv*TE+i*64+lane]=e2;
    }
    #pragma unroll
    for (int off=32; off>=1; off>>=1) sum += __shfl_xor(sum, off);
    const float r = 1.0f/sum;
    float* wout = outW + (size_t)(b*TD + s0 + wv)*TE;
    #pragma unroll
    for (int i=0;i<8;i++) wout[i*64+lane] = vals[i]*r;   // coalesced
    if (lane==0) rs[wv] = r;
  }
  __syncthreads();

  // ---- phase 3: context (thread = e column; coalesced enc reads) ----
  {
    float c0=0.f,c1=0.f,c2=0.f,c3=0.f;
    const float* encB = enc + (size_t)b*TE*DE + tid;
    #pragma unroll 2
    for (int t4=0;t4<TE/4;t4++){
      float p0[4], p1[4], p2[4], p3[4];
      *(float4*)p0 = *(const float4*)&pl[0*TE+4*t4];   // LDS broadcast b128
      *(float4*)p1 = *(const float4*)&pl[1*TE+4*t4];
      *(float4*)p2 = *(const float4*)&pl[2*TE+4*t4];
      *(float4*)p3 = *(const float4*)&pl[3*TE+4*t4];
      #pragma unroll
      for (int u=0;u<4;u++){
        const float f = encB[(size_t)(4*t4+u)*DE];
        c0 += p0[u]*f; c1 += p1[u]*f; c2 += p2[u]*f; c3 += p3[u]*f;
      }
    }
    float* cp = outCtx + (size_t)(b*TD + s0)*DE + tid;
    cp[0]      = c0*rs[0];
    cp[DE]     = c1*rs[1];
    cp[2*DE]   = c2*rs[2];
    cp[3*DE]   = c3*rs[3];
  }
}

extern "C" void kernel_launch(void* const* d_in, const int* in_sizes, int n_in,
                              void* d_out, int out_size, void* d_ws, size_t ws_size,
                              hipStream_t stream)
{
  const float* enc  = (const float*)d_in[0];
  const float* dec  = (const float*)d_in[1];
  const float* Wenc = (const float*)d_in[2];
  const float* Wdec = (const float*)d_in[3];
  const float* v    = (const float*)d_in[4];
  float* outCtx = (float*)d_out;                       // (8,256,256)
  float* outW   = outCtx + (size_t)B*TD*DE;            // (8,256,512)
  float* encWT  = (float*)d_ws;                        // 4 MB scratch

  hipLaunchKernelGGL(encw_kernel, dim3(512), dim3(256), 0, stream,
                     enc, Wenc, encWT);
  hipLaunchKernelGGL(attn_kernel, dim3(512), dim3(256), 0, stream,
                     enc, dec, Wdec, v, encWT, outCtx, outW);
}